// Round 3
// baseline (82.106 us; speedup 1.0000x reference)
//
#include <hip/hip_runtime.h>
#include <hip/hip_bf16.h>

// GaussianBasis: 2D gaussian splatting, N=10000 gaussians -> (3,256,256) fp32.
// Scatter formulation, 2 dispatches, no d_ws:
//   1) init: out[i] = shift  (so shift is pre-applied once per pixel)
//   2) splat: atomicAdd(out, (scale*color) * alpha) over each gaussian's
//      visible bbox (alpha >= 1/255 => sigma <= ln(255*op), cov bounded =>
//      bbox <= ~13x18 px, avg ~110 px => ~1.1M evals, ~1.1M atomics).
// Final out = shift + scale * sum(alpha*color)  ==  acc*scale + shift.

#define IMG_H 256
#define IMG_W 256
#define NPIX (IMG_H * IMG_W)

__device__ __forceinline__ float fast_tanh(float x) {
    // tanh(x) = 1 - 2/(exp(2x)+1); __expf rel err ~1e-5 -> center shift
    // <= ~1e-3 px, negligible vs 0.108 absmax threshold.
    const float e = __expf(2.0f * x);
    return 1.0f - 2.0f / (e + 1.0f);
}

__global__ __launch_bounds__(256) void init_kernel(
    float4* __restrict__ out, const float* __restrict__ shift)
{
    const float s = shift[0];
    out[blockIdx.x * 256 + threadIdx.x] = make_float4(s, s, s, s);
}

__global__ __launch_bounds__(256) void splat_kernel(
    const float* __restrict__ xyz,      // (N,2)
    const float* __restrict__ chol,     // (N,3)
    const float* __restrict__ colors,   // (N,3)
    const float* __restrict__ opacity,  // (N,1)
    const float* __restrict__ scale,    // (1,)
    float* __restrict__ out,            // (3,H,W) fp32, pre-filled with shift
    int N)
{
    const int wave = threadIdx.x >> 6;
    const int lane = threadIdx.x & 63;
    const int n = blockIdx.x * 4 + wave;
    if (n >= N) return;

    // Wave-uniform setup (all 64 lanes redundantly; pure VALU, cheap).
    const float cx = 0.5f * IMG_W * (fast_tanh(xyz[2 * n + 0]) + 1.0f);
    const float cy = 0.5f * IMG_H * (fast_tanh(xyz[2 * n + 1]) + 1.0f);

    const float L0 = chol[3 * n + 0] + 0.5f;
    const float L1 = chol[3 * n + 1];
    const float L2 = chol[3 * n + 2] + 0.5f;
    const float cov_xx = L0 * L0;
    const float cov_xy = L0 * L1;
    const float cov_yy = L1 * L1 + L2 * L2;
    const float det = cov_xx * cov_yy - cov_xy * cov_xy;
    const float inv_det = 1.0f / det;

    const float conic_a = cov_yy * inv_det;
    const float conic_b = -cov_xy * inv_det;
    const float conic_c = cov_xx * inv_det;

    const float op = opacity[n];
    const float smax = __logf(255.0f * op);  // alpha>=1/255 <=> sigma<=smax
    if (!(smax > 0.0f)) return;

    const float rx = __fsqrt_rn(2.0f * smax * cov_xx) + 1.0f;
    const float ry = __fsqrt_rn(2.0f * smax * cov_yy) + 1.0f;
    const int x0 = max(0, (int)floorf(cx - rx));
    const int x1 = min(IMG_W - 1, (int)ceilf(cx + rx));
    const int y0 = max(0, (int)floorf(cy - ry));
    const int y1 = min(IMG_H - 1, (int)ceilf(cy + ry));
    if (x0 > x1 || y0 > y1) return;

    const int bw = x1 - x0 + 1;          // <= 16
    const int npix = bw * (y1 - y0 + 1); // <= ~250
    const float inv_bw = 1.0f / (float)bw;

    const float s = scale[0];
    const float c0 = s * colors[3 * n + 0];
    const float c1 = s * colors[3 * n + 1];
    const float c2 = s * colors[3 * n + 2];

    for (int i = lane; i < npix; i += 64) {
        // i/bw via float recip: exact for i<~250 with +0.5 bias (0.5/bw >> eps)
        const int yy = (int)(((float)i + 0.5f) * inv_bw);
        const int xx = i - yy * bw;
        const float dx = cx - (float)(x0 + xx);
        const float dy = cy - (float)(y0 + yy);
        const float sigma =
            0.5f * (conic_a * dx * dx + conic_c * dy * dy) + conic_b * (dx * dy);
        float alpha = op * __expf(-sigma);
        if (sigma >= 0.0f && alpha >= (1.0f / 255.0f)) {
            alpha = fminf(alpha, 0.999f);
            const int pix = (y0 + yy) * IMG_W + (x0 + xx);
            atomicAdd(&out[0 * NPIX + pix], alpha * c0);
            atomicAdd(&out[1 * NPIX + pix], alpha * c1);
            atomicAdd(&out[2 * NPIX + pix], alpha * c2);
        }
    }
}

extern "C" void kernel_launch(void* const* d_in, const int* in_sizes, int n_in,
                              void* d_out, int out_size, void* d_ws, size_t ws_size,
                              hipStream_t stream) {
    const float* xyz     = (const float*)d_in[0];
    const float* chol    = (const float*)d_in[1];
    const float* colors  = (const float*)d_in[2];
    const float* opacity = (const float*)d_in[3];
    const float* scale   = (const float*)d_in[4];
    const float* shift   = (const float*)d_in[5];
    float* out = (float*)d_out;

    const int N = in_sizes[3];  // opacity is (N,1)

    // 3*256*256 floats = 49152 float4 -> 192 blocks of 256
    init_kernel<<<(3 * NPIX / 4) / 256, 256, 0, stream>>>((float4*)out, shift);
    splat_kernel<<<(N + 3) / 4, 256, 0, stream>>>(xyz, chol, colors, opacity,
                                                  scale, out, N);
}